// Round 1
// baseline (93.482 us; speedup 1.0000x reference)
//
#include <hip/hip_runtime.h>
#include <hip/hip_bf16.h>

// Problem constants (from reference): B=128, IN=256, H=128, OUT=32
#define B_   128
#define IN_  256
#define H_   128
#define OUT_ 32
#define BT   8   // batch tile per block
#define HT   8   // h tile per block

// Main kernel: grid = (H/HT, B/BT) = (16,16) blocks of 256 threads.
// Thread layout: o = tid&31, h_local = tid>>5.
// Each thread accumulates s[b] for BT batch rows at its (h, o).
__global__ __launch_bounds__(256) void o1u_main(
    const float* __restrict__ input,      // (B, IN)
    const float* __restrict__ sigma_psi,  // (IN, H, OUT)
    const float* __restrict__ chi,        // (IN, H)
    const float* __restrict__ sigma_eps,  // (H, OUT)
    const float* __restrict__ eta,        // (H, OUT)
    float* __restrict__ sum_w,            // (B, OUT) accumulators
    float* __restrict__ sum_weta)         // (B, OUT) accumulators
{
    const int tid = threadIdx.x;
    const int o  = tid & 31;
    const int hl = tid >> 5;                  // 0..7
    const int h_base = blockIdx.x * HT;
    const int b_base = blockIdx.y * BT;
    const int h = h_base + hl;

    __shared__ float x_s[BT][IN_];            // 8 KB; reads are wave-uniform broadcasts
    __shared__ float chi_s[HT][IN_ + 1];      // +1 pad: hl-strided reads hit distinct banks

    // Stage x tile (BT x IN)
    for (int idx = tid; idx < BT * IN_; idx += 256) {
        int b = idx >> 8;          // idx / IN_
        int i = idx & (IN_ - 1);   // idx % IN_
        x_s[b][i] = input[(b_base + b) * IN_ + i];
    }
    // Stage chi tile (HT x IN); chi is (IN, H) in memory
    for (int idx = tid; idx < HT * IN_; idx += 256) {
        int hh = idx >> 8;
        int i  = idx & (IN_ - 1);
        chi_s[hh][i] = chi[i * H_ + (h_base + hh)];
    }
    __syncthreads();

    float s[BT];
#pragma unroll
    for (int b = 0; b < BT; ++b) s[b] = 0.0f;

    // sigma_psi[(i*H + h)*OUT + o] — coalesced: block reads 4KB contiguous per i
    const float* sp_ptr = sigma_psi + (size_t)h * OUT_ + o;
#pragma unroll 4
    for (int i = 0; i < IN_; ++i) {
        float sp = sp_ptr[(size_t)i * (H_ * OUT_)];
        float c  = chi_s[hl][i];
#pragma unroll
        for (int b = 0; b < BT; ++b) {
            float d = sp * (c - x_s[b][i]);
            s[b] = fmaf(d, d, s[b]);
        }
    }

    const float se = sigma_eps[h * OUT_ + o];
    const float et = eta[h * OUT_ + o];
    const float se2 = se * se;

    __shared__ float red_w[HT][BT][OUT_];     // 8 KB
    __shared__ float red_we[HT][BT][OUT_];    // 8 KB
#pragma unroll
    for (int b = 0; b < BT; ++b) {
        float w = 1.0f / (s[b] + se2);
        red_w[hl][b][o]  = w;
        red_we[hl][b][o] = w * et;
    }
    __syncthreads();

    // Reduce over the HT local h's; thread -> bin (b = tid>>5, o = tid&31)
    const int rb = tid >> 5;
    const int ro = tid & 31;
    float sw = 0.0f, swe = 0.0f;
#pragma unroll
    for (int k = 0; k < HT; ++k) {
        sw  += red_w[k][rb][ro];
        swe += red_we[k][rb][ro];
    }
    atomicAdd(&sum_w[(b_base + rb) * OUT_ + ro], sw);
    atomicAdd(&sum_weta[(b_base + rb) * OUT_ + ro], swe);
}

// Epilogue: (B*OUT) threads compute post_mu and post_sigma2
__global__ __launch_bounds__(256) void o1u_final(
    const float* __restrict__ sum_w,
    const float* __restrict__ sum_weta,
    const float* __restrict__ mu_phi,     // (OUT)
    const float* __restrict__ sigma_phi,  // (OUT)
    float* __restrict__ out)              // post_mu (B*OUT) then post_sigma2 (B*OUT)
{
    const int idx = blockIdx.x * 256 + threadIdx.x;  // b*OUT + o
    if (idx >= B_ * OUT_) return;
    const int o = idx & (OUT_ - 1);
    float sp = sigma_phi[o];
    float sp2 = sp * sp;
    float denom = 1.0f + sp2 * sum_w[idx];
    float inv = 1.0f / denom;
    out[idx] = (mu_phi[o] + sp2 * sum_weta[idx]) * inv;  // post_mu
    out[B_ * OUT_ + idx] = sp2 * inv;                    // post_sigma2
}

extern "C" void kernel_launch(void* const* d_in, const int* in_sizes, int n_in,
                              void* d_out, int out_size, void* d_ws, size_t ws_size,
                              hipStream_t stream) {
    const float* input     = (const float*)d_in[0];
    const float* sigma_psi = (const float*)d_in[1];
    const float* chi       = (const float*)d_in[2];
    const float* sigma_eps = (const float*)d_in[3];
    const float* eta       = (const float*)d_in[4];
    const float* mu_phi    = (const float*)d_in[5];
    const float* sigma_phi = (const float*)d_in[6];
    float* out = (float*)d_out;
    float* ws  = (float*)d_ws;

    float* sum_w    = ws;                 // B*OUT floats
    float* sum_weta = ws + B_ * OUT_;     // B*OUT floats

    hipMemsetAsync(d_ws, 0, 2 * B_ * OUT_ * sizeof(float), stream);

    dim3 grid(H_ / HT, B_ / BT);
    o1u_main<<<grid, 256, 0, stream>>>(input, sigma_psi, chi, sigma_eps, eta,
                                       sum_w, sum_weta);
    o1u_final<<<(B_ * OUT_ + 255) / 256, 256, 0, stream>>>(sum_w, sum_weta,
                                                           mu_phi, sigma_phi, out);
}

// Round 2
// 80.258 us; speedup vs baseline: 1.1648x; 1.1648x over previous
//
#include <hip/hip_runtime.h>

// Problem constants: B=128, IN=256, H=128, OUT=32
#define B_   128
#define IN_  256
#define H_   128
#define OUT_ 32
#define HT   4                 // h per block
#define BT   8                 // b per block
#define NHB  (H_ / HT)         // 32 h-blocks
#define NBB  (B_ / BT)         // 16 b-blocks
#define DIFF_STRIDE 2056       // 2048 + 8 pad: hl-planes land on distinct bank groups
#define SM_FLOATS   (HT * DIFF_STRIDE)   // 8224 floats = 32.9 KB (aliased: diff2 then red)

// grid (NHB, NBB) = (32,16) = 512 blocks, 256 threads -> 2 blocks/CU, 8 waves/CU.
// Thread map: ig = tid>>5 (i-chunk, 0..7), hl = (tid>>3)&3, og = tid&7 (o4 = og*4).
__global__ __launch_bounds__(256, 2) void o1u_main(
    const float* __restrict__ input,      // (B, IN)
    const float* __restrict__ sigma_psi,  // (IN, H, OUT)
    const float* __restrict__ chi,        // (IN, H)
    const float* __restrict__ sigma_eps,  // (H, OUT)
    const float* __restrict__ eta,        // (H, OUT)
    float* __restrict__ sw_part,          // (NHB, B, OUT)
    float* __restrict__ swe_part)         // (NHB, B, OUT)
{
    const int tid = threadIdx.x;
    const int ig = tid >> 5;
    const int hl = (tid >> 3) & 3;
    const int og = tid & 7;
    const int hb = blockIdx.x;
    const int h_base = hb * HT;
    const int b_base = blockIdx.y * BT;

    __shared__ __align__(16) float sm[SM_FLOATS];

    // Phase 1: diff2[hh][i*8 + b] = (chi[i,h] - x[b,i])^2   (8192 elems, 32/thread)
#pragma unroll
    for (int k = 0; k < (HT * IN_ * BT) / 256; ++k) {
        int flat = k * 256 + tid;          // hh(2b) | i(8b) | b(3b)
        int b  = flat & 7;
        int i  = (flat >> 3) & 255;
        int hh = flat >> 11;
        float e = chi[i * H_ + (h_base + hh)] - input[(b_base + b) * IN_ + i];
        sm[hh * DIFF_STRIDE + (flat & 2047)] = e * e;   // consecutive lanes -> consecutive addrs
    }
    __syncthreads();

    // Phase 2: s[b][j] += sigma_psi^2 * diff2, over this thread's 32 i's
    const float* sp_base = sigma_psi + (size_t)(h_base + hl) * OUT_ + og * 4;
    const float* drow = sm + hl * DIFF_STRIDE;
    float s[BT][4];
#pragma unroll
    for (int b = 0; b < BT; ++b)
#pragma unroll
        for (int j = 0; j < 4; ++j) s[b][j] = 0.0f;

#pragma unroll 4
    for (int k = 0; k < IN_ / 8; ++k) {     // 32 iterations
        int i = ig * 32 + k;
        float4 sp = *(const float4*)(sp_base + (size_t)i * (H_ * OUT_));
        float4 sp2;
        sp2.x = sp.x * sp.x; sp2.y = sp.y * sp.y;
        sp2.z = sp.z * sp.z; sp2.w = sp.w * sp.w;
        const float4* dp = (const float4*)(drow + i * 8);
        float4 eA = dp[0];                  // b = 0..3
        float4 eB = dp[1];                  // b = 4..7
        float ev[8] = {eA.x, eA.y, eA.z, eA.w, eB.x, eB.y, eB.z, eB.w};
#pragma unroll
        for (int b = 0; b < BT; ++b) {
            s[b][0] = fmaf(sp2.x, ev[b], s[b][0]);
            s[b][1] = fmaf(sp2.y, ev[b], s[b][1]);
            s[b][2] = fmaf(sp2.z, ev[b], s[b][2]);
            s[b][3] = fmaf(sp2.w, ev[b], s[b][3]);
        }
    }

    // Phase 3: tree-reduce over the 8 i-chunks (alias sm as red[ig][1024])
    __syncthreads();
#pragma unroll
    for (int b = 0; b < BT; ++b) {
        float4 v; v.x = s[b][0]; v.y = s[b][1]; v.z = s[b][2]; v.w = s[b][3];
        *(float4*)(sm + ig * 1024 + hl * 256 + b * 32 + og * 4) = v;
    }
    __syncthreads();

    // Phase 4: each thread owns one (b,o) bin; sum over ig, apply w, reduce over hl
    const int rb = tid >> 5;
    const int ro = tid & 31;
    float sw = 0.0f, swe = 0.0f;
#pragma unroll
    for (int hh = 0; hh < HT; ++hh) {
        float sfull = 0.0f;
#pragma unroll
        for (int g = 0; g < 8; ++g)
            sfull += sm[g * 1024 + hh * 256 + rb * 32 + ro];
        float se = sigma_eps[(h_base + hh) * OUT_ + ro];
        float w = 1.0f / fmaf(se, se, sfull);
        sw += w;
        swe += w * eta[(h_base + hh) * OUT_ + ro];
    }
    sw_part[((size_t)hb * B_ + (b_base + rb)) * OUT_ + ro] = sw;
    swe_part[((size_t)hb * B_ + (b_base + rb)) * OUT_ + ro] = swe;
}

// Final: reduce the 32 h-block partials per (b,o) bin and apply the posterior.
// grid 64 x 64 threads: idx = b*OUT + o over 4096 bins.
__global__ __launch_bounds__(64) void o1u_final(
    const float* __restrict__ sw_part,
    const float* __restrict__ swe_part,
    const float* __restrict__ mu_phi,     // (OUT)
    const float* __restrict__ sigma_phi,  // (OUT)
    float* __restrict__ out)              // post_mu (B*OUT) then post_sigma2 (B*OUT)
{
    const int idx = blockIdx.x * 64 + threadIdx.x;
    const int o = idx & (OUT_ - 1);
    float sw = 0.0f, swe = 0.0f;
#pragma unroll 8
    for (int hb = 0; hb < NHB; ++hb) {
        sw  += sw_part[hb * (B_ * OUT_) + idx];
        swe += swe_part[hb * (B_ * OUT_) + idx];
    }
    float sp = sigma_phi[o];
    float sp2 = sp * sp;
    float inv = 1.0f / fmaf(sp2, sw, 1.0f);
    out[idx] = fmaf(sp2, swe, mu_phi[o]) * inv;   // post_mu
    out[B_ * OUT_ + idx] = sp2 * inv;             // post_sigma2
}

extern "C" void kernel_launch(void* const* d_in, const int* in_sizes, int n_in,
                              void* d_out, int out_size, void* d_ws, size_t ws_size,
                              hipStream_t stream) {
    const float* input     = (const float*)d_in[0];
    const float* sigma_psi = (const float*)d_in[1];
    const float* chi       = (const float*)d_in[2];
    const float* sigma_eps = (const float*)d_in[3];
    const float* eta       = (const float*)d_in[4];
    const float* mu_phi    = (const float*)d_in[5];
    const float* sigma_phi = (const float*)d_in[6];
    float* out = (float*)d_out;
    float* ws  = (float*)d_ws;

    float* sw_part  = ws;                          // NHB*B*OUT floats (512 KB)
    float* swe_part = ws + NHB * B_ * OUT_;        // NHB*B*OUT floats

    dim3 grid(NHB, NBB);
    o1u_main<<<grid, 256, 0, stream>>>(input, sigma_psi, chi, sigma_eps, eta,
                                       sw_part, swe_part);
    o1u_final<<<(B_ * OUT_) / 64, 64, 0, stream>>>(sw_part, swe_part,
                                                   mu_phi, sigma_phi, out);
}